// Round 1
// baseline (354.219 us; speedup 1.0000x reference)
//
#include <hip/hip_runtime.h>
#include <hip/hip_bf16.h>
#include <math.h>

#define NTOK 32768
#define HID  1024
#define NEXP 64
#define H4   256

typedef __attribute__((ext_vector_type(8))) short bf16x8;
typedef __attribute__((ext_vector_type(4))) float f32x4;

static __device__ __forceinline__ ushort f2bf(float x) {
    unsigned u = __float_as_uint(x);
    unsigned r = (u + 0x7FFFu + ((u >> 16) & 1u)) >> 16;   // RNE
    return (ushort)r;
}

// ---------------------------------------------------------------------------
// Kernel 0 (fused prep): blocks 0..255 split w1 into bf16 hi/lo panels;
// blocks 256..319 transpose router_w into RWT[k][64] for logits_gemm.
// ---------------------------------------------------------------------------
__global__ __launch_bounds__(256) void prep_kernel(
    const float* __restrict__ W1, const float* __restrict__ RW,
    ushort* __restrict__ W1h, ushort* __restrict__ W1l,
    float* __restrict__ RWT)
{
    if (blockIdx.x < 256) {
        const int id = blockIdx.x * 256 + threadIdx.x;
        const int c  = id >> 8;
        const int kc = id & 255;
        const int k0 = kc * 4;
        const float4 v = *(const float4*)(W1 + (size_t)c * HID + k0);
        const int p  = k0 >> 5;
        const int kk = k0 & 31;
        const size_t dst = ((size_t)p * H4 + c) * 32 + kk;
        const float xs[4] = {v.x, v.y, v.z, v.w};
        ushort hv[4], lv[4];
#pragma unroll
        for (int j = 0; j < 4; j++) {
            const ushort h = f2bf(xs[j]);
            hv[j] = h;
            lv[j] = f2bf(xs[j] - __uint_as_float(((unsigned)h) << 16));
        }
        *(ushort4*)(W1h + dst) = make_ushort4(hv[0], hv[1], hv[2], hv[3]);
        *(ushort4*)(W1l + dst) = make_ushort4(lv[0], lv[1], lv[2], lv[3]);
    } else {
        const int e = blockIdx.x - 256;              // 0..63
        const int k0 = threadIdx.x * 4;              // 0..1020
        const float4 v = *(const float4*)(RW + (size_t)e * HID + k0);
        RWT[(size_t)(k0 + 0) * NEXP + e] = v.x;
        RWT[(size_t)(k0 + 1) * NEXP + e] = v.y;
        RWT[(size_t)(k0 + 2) * NEXP + e] = v.z;
        RWT[(size_t)(k0 + 3) * NEXP + e] = v.w;
    }
}

// ---------------------------------------------------------------------------
// Kernel 1: exact fp32 router-logits GEMM v6 — K-split-4 for occupancy.
// v5 diagnosis: grid 512 blocks x 4 waves = 8 waves/CU = 25% occupancy cap
// (measured 21%, VALUBusy 27%) -> latency-bound. v6: 1024-thr blocks, wave
// w handles col-group (w&3) and K-quarter (w>>2); 8192 waves = 32/CU.
// Per-wave inner structure (lane=token, scalar W ring, static dbuf) is
// unchanged from v5 (spill-proof). One-shot padded-LDS tree combines the
// 4 K-partials deterministically; only h==0 waves store.
// ---------------------------------------------------------------------------
template<bool FULL>
__device__ __forceinline__ void tile16(const float4 (&xt)[4], int kb,
                                       const float* __restrict__ wbase,
                                       float4 (&wr)[4][4], float (&acc)[16])
{
#pragma unroll
    for (int kk = 0; kk < 16; kk++) {
        const int slot = kk & 3;                    // constant after unroll
        const float4 w0 = wr[slot][0], w1 = wr[slot][1];
        const float4 w2 = wr[slot][2], w3 = wr[slot][3];
        if (FULL || kk < 12) {                      // static guard
#pragma unroll
            for (int j = 0; j < 4; j++)
                wr[slot][j] = *(const float4*)(wbase + (size_t)(kb + kk + 4) * NEXP + j * 4);
        }
        const float4 xv4 = xt[kk >> 2];             // constant after unroll
        const float xv = (kk & 3) == 0 ? xv4.x : (kk & 3) == 1 ? xv4.y
                       : (kk & 3) == 2 ? xv4.z : xv4.w;
        acc[ 0] = fmaf(w0.x, xv, acc[ 0]); acc[ 1] = fmaf(w0.y, xv, acc[ 1]);
        acc[ 2] = fmaf(w0.z, xv, acc[ 2]); acc[ 3] = fmaf(w0.w, xv, acc[ 3]);
        acc[ 4] = fmaf(w1.x, xv, acc[ 4]); acc[ 5] = fmaf(w1.y, xv, acc[ 5]);
        acc[ 6] = fmaf(w1.z, xv, acc[ 6]); acc[ 7] = fmaf(w1.w, xv, acc[ 7]);
        acc[ 8] = fmaf(w2.x, xv, acc[ 8]); acc[ 9] = fmaf(w2.y, xv, acc[ 9]);
        acc[10] = fmaf(w2.z, xv, acc[10]); acc[11] = fmaf(w2.w, xv, acc[11]);
        acc[12] = fmaf(w3.x, xv, acc[12]); acc[13] = fmaf(w3.y, xv, acc[13]);
        acc[14] = fmaf(w3.z, xv, acc[14]); acc[15] = fmaf(w3.w, xv, acc[15]);
    }
}

__global__ __launch_bounds__(1024, 8) void logits_gemm(
    const float* __restrict__ X, const float* __restrict__ RWT,
    float* __restrict__ logits)
{
    __shared__ float red[3][64][65];                // padded: 2-way banks = free

    const int tid  = threadIdx.x;
    const int lane = tid & 63;
    const int wave = tid >> 6;                      // 0..15
    const int tok  = blockIdx.x * 64 + lane;
    const int c    = wave & 3;                      // col group (16 cols)
    const int h    = wave >> 2;                     // K quarter (256 k)
    const int colbase = __builtin_amdgcn_readfirstlane(c * 16);
    const int kbase   = __builtin_amdgcn_readfirstlane(h * 256);

    const float* __restrict__ xrow  = X + (size_t)tok * HID;
    const float* __restrict__ wbase = RWT + colbase;

    float acc[16];
#pragma unroll
    for (int q = 0; q < 16; q++) acc[q] = 0.f;

    float4 xa[4], xb[4];     // two static tile buffers (no dynamic index!)
    float4 wr[4][4];         // W ring, 4 k deep

#pragma unroll
    for (int j = 0; j < 4; j++) xa[j] = *(const float4*)(xrow + kbase + j * 4);
#pragma unroll
    for (int d = 0; d < 4; d++)
#pragma unroll
        for (int j = 0; j < 4; j++)
            wr[d][j] = *(const float4*)(wbase + (size_t)(kbase + d) * NEXP + j * 4);

    // main: k0 = kbase, kbase+32, ..., kbase+192 (two 16-k tiles per iter)
    const int kend = kbase + 256;
    for (int k0 = kbase; k0 < kend - 32; k0 += 32) {
#pragma unroll
        for (int j = 0; j < 4; j++)
            xb[j] = *(const float4*)(xrow + k0 + 16 + j * 4);
        tile16<true>(xa, k0, wbase, wr, acc);
#pragma unroll
        for (int j = 0; j < 4; j++)
            xa[j] = *(const float4*)(xrow + k0 + 32 + j * 4);
        tile16<true>(xb, k0 + 16, wbase, wr, acc);
    }
    // peel: tiles kend-32 (full refill, max k = kend-13) and kend-16 (kk<12,
    // max refill k = kend-1 -> never reads past this wave's K quarter)
    {
#pragma unroll
        for (int j = 0; j < 4; j++)
            xb[j] = *(const float4*)(xrow + (kend - 16) + j * 4);
        tile16<true>(xa, kend - 32, wbase, wr, acc);
        tile16<false>(xb, kend - 16, wbase, wr, acc);
    }

    // combine the 4 K-partials: h>0 waves dump to LDS, h==0 waves reduce+store
    if (h > 0) {
        float* dst = &red[h - 1][lane][colbase];
#pragma unroll
        for (int j = 0; j < 16; j++) dst[j] = acc[j];
    }
    __syncthreads();
    if (h == 0) {
#pragma unroll
        for (int j = 0; j < 16; j++) {
            float s = acc[j] + red[0][lane][colbase + j];
            s += red[1][lane][colbase + j];
            s += red[2][lane][colbase + j];
            acc[j] = s;
        }
#pragma unroll
        for (int j = 0; j < 4; j++) {
            float4 v = {acc[j * 4], acc[j * 4 + 1], acc[j * 4 + 2], acc[j * 4 + 3]};
            *(float4*)(logits + (size_t)tok * NEXP + colbase + j * 4) = v;
        }
    }
}

// ---------------------------------------------------------------------------
// Kernel 2: complexity predictor via split-bf16 MFMA (unchanged, proven).
// ---------------------------------------------------------------------------
__global__ __launch_bounds__(256) void pred_mfma(
    const float* __restrict__ X,
    const ushort* __restrict__ W1h, const ushort* __restrict__ W1l,
    const float* __restrict__ B1, const float* __restrict__ W2,
    float* __restrict__ s2ws)
{
    __shared__ ushort Ah[4096];
    __shared__ ushort Al[4096];
    __shared__ ushort Bh[4096];
    __shared__ ushort Bl[4096];

    const int tid  = threadIdx.x;
    const int lane = tid & 63;
    const int wave = tid >> 6;
    const int wr = wave >> 1, wc = wave & 1;
    const int quad = lane >> 4, l15 = lane & 15;
    const int tok0 = blockIdx.x * 128;
    const int cb   = blockIdx.y;

    f32x4 acc[4][4];
#pragma unroll
    for (int fi = 0; fi < 4; fi++)
#pragma unroll
        for (int fj = 0; fj < 4; fj++) acc[fi][fj] = (f32x4){0.f, 0.f, 0.f, 0.f};

    float w2r[4], b1r[4];
#pragma unroll
    for (int f = 0; f < 4; f++) {
        const int col = cb * 128 + wc * 64 + f * 16 + l15;
        w2r[f] = W2[col];
        b1r[f] = B1[col];
    }

    for (int p = 0; p < 32; ++p) {
        const int k0 = p * 32;
        __syncthreads();

        {
            const size_t tile = ((size_t)p * H4 + cb * 128) * 32;
#pragma unroll
            for (int i = 0; i < 2; ++i) {
                const int j = i * 256 + tid;
                __builtin_amdgcn_global_load_lds(
                    (const __attribute__((address_space(1))) void*)(W1h + tile + (size_t)j * 8),
                    (__attribute__((address_space(3))) void*)((char*)Bh + (size_t)j * 16),
                    16, 0, 0);
                __builtin_amdgcn_global_load_lds(
                    (const __attribute__((address_space(1))) void*)(W1l + tile + (size_t)j * 8),
                    (__attribute__((address_space(3))) void*)((char*)Bl + (size_t)j * 16),
                    16, 0, 0);
            }
        }

#pragma unroll
        for (int it = 0; it < 4; ++it) {
            const int idx = it * 256 + tid;
            const int t   = idx >> 3;
            const int kc  = idx & 7;
            const float4 v = *(const float4*)(X + (size_t)(tok0 + t) * HID + k0 + kc * 4);
            const float xs[4] = {v.x, v.y, v.z, v.w};
            ushort hv[4], lv[4];
#pragma unroll
            for (int j = 0; j < 4; j++) {
                const ushort h = f2bf(xs[j]);
                hv[j] = h;
                lv[j] = f2bf(xs[j] - __uint_as_float(((unsigned)h) << 16));
            }
            const int a = t * 32 + kc * 4;
            *(ushort4*)&Ah[a] = make_ushort4(hv[0], hv[1], hv[2], hv[3]);
            *(ushort4*)&Al[a] = make_ushort4(lv[0], lv[1], lv[2], lv[3]);
        }
        __syncthreads();

        bf16x8 a_h[4], a_l[4], b_h[4], b_l[4];
#pragma unroll
        for (int f = 0; f < 4; ++f) {
            const int ra = (wr * 64 + f * 16 + l15) * 32 + quad * 8;
            const int rb = (wc * 64 + f * 16 + l15) * 32 + quad * 8;
            a_h[f] = *(const bf16x8*)&Ah[ra];
            a_l[f] = *(const bf16x8*)&Al[ra];
            b_h[f] = *(const bf16x8*)&Bh[rb];
            b_l[f] = *(const bf16x8*)&Bl[rb];
        }
#pragma unroll
        for (int fi = 0; fi < 4; ++fi)
#pragma unroll
            for (int fj = 0; fj < 4; ++fj) {
                acc[fi][fj] = __builtin_amdgcn_mfma_f32_16x16x32_bf16(a_h[fi], b_h[fj], acc[fi][fj], 0, 0, 0);
                acc[fi][fj] = __builtin_amdgcn_mfma_f32_16x16x32_bf16(a_l[fi], b_h[fj], acc[fi][fj], 0, 0, 0);
                acc[fi][fj] = __builtin_amdgcn_mfma_f32_16x16x32_bf16(a_h[fi], b_l[fj], acc[fi][fj], 0, 0, 0);
            }
    }

#pragma unroll
    for (int fi = 0; fi < 4; ++fi) {
#pragma unroll
        for (int r = 0; r < 4; ++r) {
            float s = 0.f;
#pragma unroll
            for (int fj = 0; fj < 4; ++fj) {
                const float hval = acc[fi][fj][r] + b1r[fj];
                s = fmaf(w2r[fj], fmaxf(hval, 0.f), s);
            }
            s += __shfl_xor(s, 1);
            s += __shfl_xor(s, 2);
            s += __shfl_xor(s, 4);
            s += __shfl_xor(s, 8);
            if (l15 == 0)
                atomicAdd(&s2ws[tok0 + wr * 64 + fi * 16 + quad * 4 + r], s);
        }
    }
}

// ---------------------------------------------------------------------------
// Kernel 3: per-token routing (unchanged, proven fast)
// ---------------------------------------------------------------------------
__global__ __launch_bounds__(64) void route_kernel(
    const float* __restrict__ logits, const float* __restrict__ s2ws,
    const float* __restrict__ B2, float* __restrict__ sel,
    float* __restrict__ wts, float* __restrict__ load_sum,
    float* __restrict__ ent_sum)
{
    const int lane = threadIdx.x;
    const int tok  = blockIdx.x * 64 + lane;

    float r[64];
    const float* lr = logits + (size_t)tok * NEXP;
#pragma unroll
    for (int e4 = 0; e4 < 16; e4++) {
        float4 v = *(const float4*)(lr + e4 * 4);
        r[e4 * 4 + 0] = v.x; r[e4 * 4 + 1] = v.y;
        r[e4 * 4 + 2] = v.z; r[e4 * 4 + 3] = v.w;
    }

    float v0 = -1e30f, v1 = -1e30f, v2 = -1e30f, v3 = -1e30f;
    int   i0 = 0, i1 = 0, i2 = 0, i3 = 0;
#pragma unroll
    for (int e = 0; e < 64; e++) {
        const float v = r[e];
        if (v > v3) {
            if (v > v2) {
                if (v > v1) {
                    if (v > v0) { v3=v2;i3=i2; v2=v1;i2=i1; v1=v0;i1=i0; v0=v;i0=e; }
                    else        { v3=v2;i3=i2; v2=v1;i2=i1; v1=v;i1=e; }
                } else          { v3=v2;i3=i2; v2=v;i2=e; }
            } else              { v3=v;i3=e; }
        }
    }

    const float s2 = s2ws[tok] + B2[0];
    const bool k4 = (s2 > 0.f);

    float w0, w1v, w2v, w3v;
    int   s1i, s2i, s3i;
    if (k4) {
        const float e0 = expf(v0 - v0), e1 = expf(v1 - v0);
        const float e2 = expf(v2 - v0), e3 = expf(v3 - v0);
        const float inv4 = 1.f / (e0 + e1 + e2 + e3);
        w0 = e0 * inv4; w1v = e1 * inv4; w2v = e2 * inv4; w3v = e3 * inv4;
        s1i = i1; s2i = i2; s3i = i3;
    } else {
        w0 = 1.f; w1v = 0.f; w2v = 0.f; w3v = 0.f;
        s1i = 0; s2i = 0; s3i = 0;
    }
    {
        float4 sv = {(float)i0, (float)s1i, (float)s2i, (float)s3i};
        float4 wv = {w0, w1v, w2v, w3v};
        *(float4*)(sel + (size_t)tok * 4) = sv;
        *(float4*)(wts + (size_t)tok * 4) = wv;
    }

    const float mx = v0;
    float S = 0.f, pz = 0.f;
#pragma unroll
    for (int e = 0; e < 64; e++) {
        const float z = r[e] - mx;
        const float t = expf(z);
        S += t; pz = fmaf(t, z, pz);
        r[e] = t;
    }
    const float inv = 1.f / S;
    float ent = logf(S) - pz * inv;

    float myload = 0.f;
#pragma unroll
    for (int e = 0; e < 64; e++) {
        float s = r[e] * inv;
        s += __shfl_xor(s, 1);
        s += __shfl_xor(s, 2);
        s += __shfl_xor(s, 4);
        s += __shfl_xor(s, 8);
        s += __shfl_xor(s, 16);
        s += __shfl_xor(s, 32);
        if (lane == e) myload = s;
    }
    atomicAdd(&load_sum[lane], myload);

    ent += __shfl_xor(ent, 1);
    ent += __shfl_xor(ent, 2);
    ent += __shfl_xor(ent, 4);
    ent += __shfl_xor(ent, 8);
    ent += __shfl_xor(ent, 16);
    ent += __shfl_xor(ent, 32);
    if (lane == 0) atomicAdd(ent_sum, ent);
}

__global__ void finalize_kernel(const float* __restrict__ load_sum,
                                const float* __restrict__ ent_sum,
                                float* __restrict__ out_scal)
{
    const int lane = threadIdx.x;
    const float le = load_sum[lane] * (1.f / (float)NTOK);
    float s = le;
#pragma unroll
    for (int o = 32; o >= 1; o >>= 1) s += __shfl_xor(s, o);
    const float mean = s * (1.f / 64.f);
    const float d = le - mean;
    float v = d * d;
#pragma unroll
    for (int o = 32; o >= 1; o >>= 1) v += __shfl_xor(v, o);
    if (lane == 0) {
        out_scal[0] = v * (1.f / 63.f);
        out_scal[1] = ent_sum[0] * (1.f / (float)NTOK);
    }
}

extern "C" void kernel_launch(void* const* d_in, const int* in_sizes, int n_in,
                              void* d_out, int out_size, void* d_ws, size_t ws_size,
                              hipStream_t stream) {
    const float* X  = (const float*)d_in[0];
    const float* RW = (const float*)d_in[1];
    const float* W1 = (const float*)d_in[2];
    const float* B1 = (const float*)d_in[3];
    const float* W2 = (const float*)d_in[4];
    const float* B2 = (const float*)d_in[5];

    float* out    = (float*)d_out;
    float* logits = out;
    float* sel    = out + (size_t)NTOK * NEXP;
    float* wts    = sel + (size_t)NTOK * 4;
    float* scal   = wts + (size_t)NTOK * 4;

    float* s2ws     = (float*)d_ws;                       // [32768]
    float* load_sum = s2ws + NTOK;                        // [64]
    float* ent_sum  = load_sum + 64;                      // [1]
    ushort* W1h = (ushort*)(s2ws + NTOK + 256);           // 512 KB
    ushort* W1l = W1h + (size_t)H4 * HID;                 // 512 KB
    float*  RWT = (float*)(W1l + (size_t)H4 * HID);       // 256 KB, [1024][64]

    hipMemsetAsync(d_ws, 0, (size_t)(NTOK + 65) * sizeof(float), stream);

    prep_kernel<<<320, 256, 0, stream>>>(W1, RW, W1h, W1l, RWT);
    logits_gemm<<<NTOK / 64, 1024, 0, stream>>>(X, RWT, logits);
    pred_mfma<<<dim3(NTOK / 128, 2), 256, 0, stream>>>(X, W1h, W1l, B1, W2, s2ws);
    route_kernel<<<NTOK / 64, 64, 0, stream>>>(logits, s2ws, B2, sel, wts, load_sum, ent_sum);
    finalize_kernel<<<1, 64, 0, stream>>>(load_sum, ent_sum, scal);
}

// Round 2
// 313.255 us; speedup vs baseline: 1.1308x; 1.1308x over previous
//
#include <hip/hip_runtime.h>
#include <hip/hip_bf16.h>
#include <math.h>

#define NTOK 32768
#define HID  1024
#define NEXP 64
#define H4   256

typedef __attribute__((ext_vector_type(8))) short bf16x8;
typedef __attribute__((ext_vector_type(8))) unsigned short ushort8v;
typedef __attribute__((ext_vector_type(4))) float f32x4;

static __device__ __forceinline__ ushort f2bf(float x) {
    unsigned u = __float_as_uint(x);
    unsigned r = (u + 0x7FFFu + ((u >> 16) & 1u)) >> 16;   // RNE
    return (ushort)r;
}

// Exact 3-way truncation split: x == bf(h) + bf(m) + bf(l) EXACTLY
// (24 mantissa bits = 8+8+8; residual after two extractions has <=8
// significant bits so the last piece is lossless).
static __device__ __forceinline__ void split3t(float x, ushort &h, ushort &m, ushort &l) {
    const unsigned u0 = __float_as_uint(x);
    h = (ushort)(u0 >> 16);
    const float r1 = x - __uint_as_float(u0 & 0xFFFF0000u);
    const unsigned u1 = __float_as_uint(r1);
    m = (ushort)(u1 >> 16);
    const float r2 = r1 - __uint_as_float(u1 & 0xFFFF0000u);
    l = (ushort)(__float_as_uint(r2) >> 16);
}

// LDS tile swizzle (ushort units): row-major [64][32] ushort tiles read as
// ds_read_b128 per (row, 8k-chunk) are 8-way bank conflicted; XOR of row
// bits into the chunk bits spreads 16-lane groups over 8 distinct 16B slots
// (2-way = free, m136). Write side uses the same XOR (both-sides rule).
#define SWZ(row, us) ((us) ^ (((row) & 7) << 3))

// ---------------------------------------------------------------------------
// Kernel 0 (fused prep): blocks 0..255 split w1 into bf16 hi/lo panels;
// blocks 256..319 split router_w 3-way into MFMA B-panels RWh/m/l
// ([p][64 cols][32 k] ushort, p = k/32).
// ---------------------------------------------------------------------------
__global__ __launch_bounds__(256) void prep_kernel(
    const float* __restrict__ W1, const float* __restrict__ RW,
    ushort* __restrict__ W1h, ushort* __restrict__ W1l,
    ushort* __restrict__ RWh, ushort* __restrict__ RWm, ushort* __restrict__ RWl)
{
    if (blockIdx.x < 256) {
        const int id = blockIdx.x * 256 + threadIdx.x;
        const int c  = id >> 8;
        const int kc = id & 255;
        const int k0 = kc * 4;
        const float4 v = *(const float4*)(W1 + (size_t)c * HID + k0);
        const int p  = k0 >> 5;
        const int kk = k0 & 31;
        const size_t dst = ((size_t)p * H4 + c) * 32 + kk;
        const float xs[4] = {v.x, v.y, v.z, v.w};
        ushort hv[4], lv[4];
#pragma unroll
        for (int j = 0; j < 4; j++) {
            const ushort h = f2bf(xs[j]);
            hv[j] = h;
            lv[j] = f2bf(xs[j] - __uint_as_float(((unsigned)h) << 16));
        }
        *(ushort4*)(W1h + dst) = make_ushort4(hv[0], hv[1], hv[2], hv[3]);
        *(ushort4*)(W1l + dst) = make_ushort4(lv[0], lv[1], lv[2], lv[3]);
    } else {
        const int e  = blockIdx.x - 256;             // expert = B column, 0..63
        const int k0 = threadIdx.x * 4;              // 0..1020
        const float4 v = *(const float4*)(RW + (size_t)e * HID + k0);
        const float xs[4] = {v.x, v.y, v.z, v.w};
        ushort h[4], m[4], l[4];
#pragma unroll
        for (int j = 0; j < 4; j++) split3t(xs[j], h[j], m[j], l[j]);
        const size_t dst = ((size_t)(k0 >> 5) * NEXP + e) * 32 + (k0 & 31);
        *(ushort4*)(RWh + dst) = make_ushort4(h[0], h[1], h[2], h[3]);
        *(ushort4*)(RWm + dst) = make_ushort4(m[0], m[1], m[2], m[3]);
        *(ushort4*)(RWl + dst) = make_ushort4(l[0], l[1], l[2], l[3]);
    }
}

// ---------------------------------------------------------------------------
// Kernel 1 (v7): router-logits via MFMA with EXACT 3-way bf16 splits.
// v6 post-mortem: VALU GEMM has a 27 µs issue-rate floor; occupancy fix
// (21->72%) left VALUBusy at 29% -> structural, not schedulable. v7 moves
// the GEMM to the matrix pipe. Accuracy: x,w split exactly 3-way; keep the
// 6 products >= 2^-16 rel (hh,hm,mh,hl,lh,mm); dropped terms ~2^-24 rel
// -> logits error ~5e-7, same class as fp32 summation-order noise (which
// passed with zero top-k flips). 64-tok blocks, 4 waves (2x2), X and B
// staged in XOR-swizzled LDS, next-k prefetch to regs under MFMA phase.
// ---------------------------------------------------------------------------
__global__ __launch_bounds__(256) void logits_mfma(
    const float* __restrict__ X,
    const ushort* __restrict__ RWh, const ushort* __restrict__ RWm,
    const ushort* __restrict__ RWl,
    float* __restrict__ logits)
{
    __shared__ __align__(16) ushort Xh[2048], Xm[2048], Xl[2048];   // [64 tok][32 k]
    __shared__ __align__(16) ushort Bh[2048], Bm[2048], Bl[2048];   // [64 col][32 k]

    const int tid  = threadIdx.x;
    const int lane = tid & 63;
    const int wave = tid >> 6;          // 0..3
    const int wr   = wave >> 1;         // token half (32 tok)
    const int wc   = wave & 1;          // col half (32 cols)
    const int quad = lane >> 4, l15 = lane & 15;
    const int tok0 = blockIdx.x * 64;

    // staging assignment: 64 rows x 32 k, 8 elems/thread
    const int t  = tid >> 2;            // 0..63 (X row / B col)
    const int kc = tid & 3;             // 0..3  (8-elem k-chunk)

    f32x4 acc[2][2];
#pragma unroll
    for (int fi = 0; fi < 2; fi++)
#pragma unroll
        for (int fj = 0; fj < 2; fj++) acc[fi][fj] = (f32x4){0.f, 0.f, 0.f, 0.f};

    const float* __restrict__ xsrc = X + (size_t)(tok0 + t) * HID + kc * 8;

    // prologue prefetch (p = 0)
    float4 xv0 = *(const float4*)(xsrc);
    float4 xv1 = *(const float4*)(xsrc + 4);
    bf16x8 bvh, bvm, bvl;
    {
        const size_t boff = (size_t)t * 32 + kc * 8;
        bvh = *(const bf16x8*)(RWh + boff);
        bvm = *(const bf16x8*)(RWm + boff);
        bvl = *(const bf16x8*)(RWl + boff);
    }

    for (int p = 0; p < 32; ++p) {
        // ---- convert + stage current tile ----
        {
            const float xs[8] = {xv0.x, xv0.y, xv0.z, xv0.w, xv1.x, xv1.y, xv1.z, xv1.w};
            ushort8v ph, pm, pl;
#pragma unroll
            for (int j = 0; j < 8; j++) {
                ushort h, m, l;
                split3t(xs[j], h, m, l);
                ph[j] = h; pm[j] = m; pl[j] = l;
            }
            const int us = SWZ(t, t * 32 + kc * 8);
            *(ushort8v*)&Xh[us] = ph;
            *(ushort8v*)&Xm[us] = pm;
            *(ushort8v*)&Xl[us] = pl;
            *(bf16x8*)&Bh[us] = bvh;
            *(bf16x8*)&Bm[us] = bvm;
            *(bf16x8*)&Bl[us] = bvl;
        }
        __syncthreads();

        // ---- prefetch next k-step to regs (latency hides under MFMA) ----
        const int pn = (p + 1) & 31;    // wraps to 0 on last iter (harmless)
        xv0 = *(const float4*)(xsrc + pn * 32);
        xv1 = *(const float4*)(xsrc + pn * 32 + 4);
        {
            const size_t boff = ((size_t)pn * NEXP + t) * 32 + kc * 8;
            bvh = *(const bf16x8*)(RWh + boff);
            bvm = *(const bf16x8*)(RWm + boff);
            bvl = *(const bf16x8*)(RWl + boff);
        }

        // ---- fragments from LDS ----
        bf16x8 ah[2], am[2], al[2], bh[2], bm[2], bl[2];
#pragma unroll
        for (int f = 0; f < 2; ++f) {
            const int rowa = wr * 32 + f * 16 + l15;
            const int ua = SWZ(rowa, rowa * 32 + quad * 8);
            ah[f] = *(const bf16x8*)&Xh[ua];
            am[f] = *(const bf16x8*)&Xm[ua];
            al[f] = *(const bf16x8*)&Xl[ua];
            const int rowb = wc * 32 + f * 16 + l15;
            const int ub = SWZ(rowb, rowb * 32 + quad * 8);
            bh[f] = *(const bf16x8*)&Bh[ub];
            bm[f] = *(const bf16x8*)&Bm[ub];
            bl[f] = *(const bf16x8*)&Bl[ub];
        }

        // ---- 6-product exact-split MFMA ----
#pragma unroll
        for (int fi = 0; fi < 2; ++fi)
#pragma unroll
            for (int fj = 0; fj < 2; ++fj) {
                acc[fi][fj] = __builtin_amdgcn_mfma_f32_16x16x32_bf16(ah[fi], bh[fj], acc[fi][fj], 0, 0, 0);
                acc[fi][fj] = __builtin_amdgcn_mfma_f32_16x16x32_bf16(am[fi], bh[fj], acc[fi][fj], 0, 0, 0);
                acc[fi][fj] = __builtin_amdgcn_mfma_f32_16x16x32_bf16(ah[fi], bm[fj], acc[fi][fj], 0, 0, 0);
                acc[fi][fj] = __builtin_amdgcn_mfma_f32_16x16x32_bf16(al[fi], bh[fj], acc[fi][fj], 0, 0, 0);
                acc[fi][fj] = __builtin_amdgcn_mfma_f32_16x16x32_bf16(ah[fi], bl[fj], acc[fi][fj], 0, 0, 0);
                acc[fi][fj] = __builtin_amdgcn_mfma_f32_16x16x32_bf16(am[fi], bm[fj], acc[fi][fj], 0, 0, 0);
            }
        __syncthreads();
    }

    // epilogue: C/D layout row = quad*4 + r (tokens), col = l15 (verified m89/m91)
#pragma unroll
    for (int fi = 0; fi < 2; ++fi)
#pragma unroll
        for (int fj = 0; fj < 2; ++fj)
#pragma unroll
            for (int r = 0; r < 4; ++r)
                logits[(size_t)(tok0 + wr * 32 + fi * 16 + quad * 4 + r) * NEXP
                       + wc * 32 + fj * 16 + l15] = acc[fi][fj][r];
}

// ---------------------------------------------------------------------------
// Kernel 2: complexity predictor via split-bf16 MFMA (unchanged, proven).
// ---------------------------------------------------------------------------
__global__ __launch_bounds__(256) void pred_mfma(
    const float* __restrict__ X,
    const ushort* __restrict__ W1h, const ushort* __restrict__ W1l,
    const float* __restrict__ B1, const float* __restrict__ W2,
    float* __restrict__ s2ws)
{
    __shared__ ushort Ah[4096];
    __shared__ ushort Al[4096];
    __shared__ ushort Bh[4096];
    __shared__ ushort Bl[4096];

    const int tid  = threadIdx.x;
    const int lane = tid & 63;
    const int wave = tid >> 6;
    const int wr = wave >> 1, wc = wave & 1;
    const int quad = lane >> 4, l15 = lane & 15;
    const int tok0 = blockIdx.x * 128;
    const int cb   = blockIdx.y;

    f32x4 acc[4][4];
#pragma unroll
    for (int fi = 0; fi < 4; fi++)
#pragma unroll
        for (int fj = 0; fj < 4; fj++) acc[fi][fj] = (f32x4){0.f, 0.f, 0.f, 0.f};

    float w2r[4], b1r[4];
#pragma unroll
    for (int f = 0; f < 4; f++) {
        const int col = cb * 128 + wc * 64 + f * 16 + l15;
        w2r[f] = W2[col];
        b1r[f] = B1[col];
    }

    for (int p = 0; p < 32; ++p) {
        const int k0 = p * 32;
        __syncthreads();

        {
            const size_t tile = ((size_t)p * H4 + cb * 128) * 32;
#pragma unroll
            for (int i = 0; i < 2; ++i) {
                const int j = i * 256 + tid;
                __builtin_amdgcn_global_load_lds(
                    (const __attribute__((address_space(1))) void*)(W1h + tile + (size_t)j * 8),
                    (__attribute__((address_space(3))) void*)((char*)Bh + (size_t)j * 16),
                    16, 0, 0);
                __builtin_amdgcn_global_load_lds(
                    (const __attribute__((address_space(1))) void*)(W1l + tile + (size_t)j * 8),
                    (__attribute__((address_space(3))) void*)((char*)Bl + (size_t)j * 16),
                    16, 0, 0);
            }
        }

#pragma unroll
        for (int it = 0; it < 4; ++it) {
            const int idx = it * 256 + tid;
            const int t   = idx >> 3;
            const int kc  = idx & 7;
            const float4 v = *(const float4*)(X + (size_t)(tok0 + t) * HID + k0 + kc * 4);
            const float xs[4] = {v.x, v.y, v.z, v.w};
            ushort hv[4], lv[4];
#pragma unroll
            for (int j = 0; j < 4; j++) {
                const ushort h = f2bf(xs[j]);
                hv[j] = h;
                lv[j] = f2bf(xs[j] - __uint_as_float(((unsigned)h) << 16));
            }
            const int a = t * 32 + kc * 4;
            *(ushort4*)&Ah[a] = make_ushort4(hv[0], hv[1], hv[2], hv[3]);
            *(ushort4*)&Al[a] = make_ushort4(lv[0], lv[1], lv[2], lv[3]);
        }
        __syncthreads();

        bf16x8 a_h[4], a_l[4], b_h[4], b_l[4];
#pragma unroll
        for (int f = 0; f < 4; ++f) {
            const int ra = (wr * 64 + f * 16 + l15) * 32 + quad * 8;
            const int rb = (wc * 64 + f * 16 + l15) * 32 + quad * 8;
            a_h[f] = *(const bf16x8*)&Ah[ra];
            a_l[f] = *(const bf16x8*)&Al[ra];
            b_h[f] = *(const bf16x8*)&Bh[rb];
            b_l[f] = *(const bf16x8*)&Bl[rb];
        }
#pragma unroll
        for (int fi = 0; fi < 4; ++fi)
#pragma unroll
            for (int fj = 0; fj < 4; ++fj) {
                acc[fi][fj] = __builtin_amdgcn_mfma_f32_16x16x32_bf16(a_h[fi], b_h[fj], acc[fi][fj], 0, 0, 0);
                acc[fi][fj] = __builtin_amdgcn_mfma_f32_16x16x32_bf16(a_l[fi], b_h[fj], acc[fi][fj], 0, 0, 0);
                acc[fi][fj] = __builtin_amdgcn_mfma_f32_16x16x32_bf16(a_h[fi], b_l[fj], acc[fi][fj], 0, 0, 0);
            }
    }

#pragma unroll
    for (int fi = 0; fi < 4; ++fi) {
#pragma unroll
        for (int r = 0; r < 4; ++r) {
            float s = 0.f;
#pragma unroll
            for (int fj = 0; fj < 4; ++fj) {
                const float hval = acc[fi][fj][r] + b1r[fj];
                s = fmaf(w2r[fj], fmaxf(hval, 0.f), s);
            }
            s += __shfl_xor(s, 1);
            s += __shfl_xor(s, 2);
            s += __shfl_xor(s, 4);
            s += __shfl_xor(s, 8);
            if (l15 == 0)
                atomicAdd(&s2ws[tok0 + wr * 64 + fi * 16 + quad * 4 + r], s);
        }
    }
}

// ---------------------------------------------------------------------------
// Kernel 3: per-token routing (unchanged, proven fast)
// ---------------------------------------------------------------------------
__global__ __launch_bounds__(64) void route_kernel(
    const float* __restrict__ logits, const float* __restrict__ s2ws,
    const float* __restrict__ B2, float* __restrict__ sel,
    float* __restrict__ wts, float* __restrict__ load_sum,
    float* __restrict__ ent_sum)
{
    const int lane = threadIdx.x;
    const int tok  = blockIdx.x * 64 + lane;

    float r[64];
    const float* lr = logits + (size_t)tok * NEXP;
#pragma unroll
    for (int e4 = 0; e4 < 16; e4++) {
        float4 v = *(const float4*)(lr + e4 * 4);
        r[e4 * 4 + 0] = v.x; r[e4 * 4 + 1] = v.y;
        r[e4 * 4 + 2] = v.z; r[e4 * 4 + 3] = v.w;
    }

    float v0 = -1e30f, v1 = -1e30f, v2 = -1e30f, v3 = -1e30f;
    int   i0 = 0, i1 = 0, i2 = 0, i3 = 0;
#pragma unroll
    for (int e = 0; e < 64; e++) {
        const float v = r[e];
        if (v > v3) {
            if (v > v2) {
                if (v > v1) {
                    if (v > v0) { v3=v2;i3=i2; v2=v1;i2=i1; v1=v0;i1=i0; v0=v;i0=e; }
                    else        { v3=v2;i3=i2; v2=v1;i2=i1; v1=v;i1=e; }
                } else          { v3=v2;i3=i2; v2=v;i2=e; }
            } else              { v3=v;i3=e; }
        }
    }

    const float s2 = s2ws[tok] + B2[0];
    const bool k4 = (s2 > 0.f);

    float w0, w1v, w2v, w3v;
    int   s1i, s2i, s3i;
    if (k4) {
        const float e0 = expf(v0 - v0), e1 = expf(v1 - v0);
        const float e2 = expf(v2 - v0), e3 = expf(v3 - v0);
        const float inv4 = 1.f / (e0 + e1 + e2 + e3);
        w0 = e0 * inv4; w1v = e1 * inv4; w2v = e2 * inv4; w3v = e3 * inv4;
        s1i = i1; s2i = i2; s3i = i3;
    } else {
        w0 = 1.f; w1v = 0.f; w2v = 0.f; w3v = 0.f;
        s1i = 0; s2i = 0; s3i = 0;
    }
    {
        float4 sv = {(float)i0, (float)s1i, (float)s2i, (float)s3i};
        float4 wv = {w0, w1v, w2v, w3v};
        *(float4*)(sel + (size_t)tok * 4) = sv;
        *(float4*)(wts + (size_t)tok * 4) = wv;
    }

    const float mx = v0;
    float S = 0.f, pz = 0.f;
#pragma unroll
    for (int e = 0; e < 64; e++) {
        const float z = r[e] - mx;
        const float t = expf(z);
        S += t; pz = fmaf(t, z, pz);
        r[e] = t;
    }
    const float inv = 1.f / S;
    float ent = logf(S) - pz * inv;

    float myload = 0.f;
#pragma unroll
    for (int e = 0; e < 64; e++) {
        float s = r[e] * inv;
        s += __shfl_xor(s, 1);
        s += __shfl_xor(s, 2);
        s += __shfl_xor(s, 4);
        s += __shfl_xor(s, 8);
        s += __shfl_xor(s, 16);
        s += __shfl_xor(s, 32);
        if (lane == e) myload = s;
    }
    atomicAdd(&load_sum[lane], myload);

    ent += __shfl_xor(ent, 1);
    ent += __shfl_xor(ent, 2);
    ent += __shfl_xor(ent, 4);
    ent += __shfl_xor(ent, 8);
    ent += __shfl_xor(ent, 16);
    ent += __shfl_xor(ent, 32);
    if (lane == 0) atomicAdd(ent_sum, ent);
}

__global__ void finalize_kernel(const float* __restrict__ load_sum,
                                const float* __restrict__ ent_sum,
                                float* __restrict__ out_scal)
{
    const int lane = threadIdx.x;
    const float le = load_sum[lane] * (1.f / (float)NTOK);
    float s = le;
#pragma unroll
    for (int o = 32; o >= 1; o >>= 1) s += __shfl_xor(s, o);
    const float mean = s * (1.f / 64.f);
    const float d = le - mean;
    float v = d * d;
#pragma unroll
    for (int o = 32; o >= 1; o >>= 1) v += __shfl_xor(v, o);
    if (lane == 0) {
        out_scal[0] = v * (1.f / 63.f);
        out_scal[1] = ent_sum[0] * (1.f / (float)NTOK);
    }
}

extern "C" void kernel_launch(void* const* d_in, const int* in_sizes, int n_in,
                              void* d_out, int out_size, void* d_ws, size_t ws_size,
                              hipStream_t stream) {
    const float* X  = (const float*)d_in[0];
    const float* RW = (const float*)d_in[1];
    const float* W1 = (const float*)d_in[2];
    const float* B1 = (const float*)d_in[3];
    const float* W2 = (const float*)d_in[4];
    const float* B2 = (const float*)d_in[5];

    float* out    = (float*)d_out;
    float* logits = out;
    float* sel    = out + (size_t)NTOK * NEXP;
    float* wts    = sel + (size_t)NTOK * 4;
    float* scal   = wts + (size_t)NTOK * 4;

    float* s2ws     = (float*)d_ws;                       // [32768]
    float* load_sum = s2ws + NTOK;                        // [64]
    float* ent_sum  = load_sum + 64;                      // [1]
    ushort* W1h = (ushort*)(s2ws + NTOK + 256);           // 512 KB
    ushort* W1l = W1h + (size_t)H4 * HID;                 // 512 KB
    ushort* RWh = W1l + (size_t)H4 * HID;                 // 128 KB  [16p][64c][32k]
    ushort* RWm = RWh + (size_t)NEXP * HID;               // 128 KB  (p here = k/32, 32 panels)
    ushort* RWl = RWm + (size_t)NEXP * HID;               // 128 KB

    hipMemsetAsync(d_ws, 0, (size_t)(NTOK + 65) * sizeof(float), stream);

    prep_kernel<<<320, 256, 0, stream>>>(W1, RW, W1h, W1l, RWh, RWm, RWl);
    logits_mfma<<<NTOK / 64, 256, 0, stream>>>(X, RWh, RWm, RWl, logits);
    pred_mfma<<<dim3(NTOK / 128, 2), 256, 0, stream>>>(X, W1h, W1l, B1, W2, s2ws);
    route_kernel<<<NTOK / 64, 64, 0, stream>>>(logits, s2ws, B2, sel, wts, load_sum, ent_sum);
    finalize_kernel<<<1, 64, 0, stream>>>(load_sum, ent_sum, scal);
}

// Round 4
// 290.148 us; speedup vs baseline: 1.2208x; 1.0796x over previous
//
#include <hip/hip_runtime.h>
#include <hip/hip_bf16.h>
#include <math.h>

#define NTOK 32768
#define HID  1024
#define NEXP 64
#define H4   256

typedef __attribute__((ext_vector_type(8))) short bf16x8;
typedef __attribute__((ext_vector_type(4))) float f32x4;

static __device__ __forceinline__ ushort f2bf(float x) {
    unsigned u = __float_as_uint(x);
    unsigned r = (u + 0x7FFFu + ((u >> 16) & 1u)) >> 16;   // RNE
    return (ushort)r;
}

// RNE-cascade 3-way split. (h, m) are BIT-IDENTICAL to the proven pred
// split (f2bf(x), f2bf(x - bf(h))); l extends it for the logits path.
// x = h + m + l + O(2^-27 |x|).
static __device__ __forceinline__ void split3r(float x, ushort &h, ushort &m, ushort &l) {
    h = f2bf(x);
    const float r1 = x - __uint_as_float(((unsigned)h) << 16);
    m = f2bf(r1);
    const float r2 = r1 - __uint_as_float(((unsigned)m) << 16);
    l = f2bf(r2);
}

// LDS hash (ushort units) for [R][32]-ushort tiles: both writer and reader
// apply the same address map, so consistency holds (bijective involution;
// this exact scheme passed in round-2's logits_mfma). Spreads a 16-lane
// column read over the banks (2-way = free).
#define SWZ(row, us) ((us) ^ (((row) & 7) << 3))

// ---------------------------------------------------------------------------
// Kernel 0 (prep): blocks 0..255 split w1 2-way RNE (bit-exact vs previous)
// into PRE-SWIZZLED panels [p][f(256x32)]; blocks 256..319 split router_w
// 3-way RNE-cascade into pre-swizzled panels [p][f(64x32)].
// Pre-swizzled global layout lets the fused kernel use global_load_lds
// (linear LDS dest) while fragment reads apply the same SWZ map.
// ---------------------------------------------------------------------------
__global__ __launch_bounds__(256) void prep_kernel(
    const float* __restrict__ W1, const float* __restrict__ RW,
    ushort* __restrict__ W1h, ushort* __restrict__ W1l,
    ushort* __restrict__ RWh, ushort* __restrict__ RWm, ushort* __restrict__ RWl)
{
    if (blockIdx.x < 256) {
        const int id = blockIdx.x * 256 + threadIdx.x;
        const int c  = id >> 8;                      // 0..255 (w1 output col)
        const int k0 = (id & 255) * 4;               // 0..1020
        const float4 v = *(const float4*)(W1 + (size_t)c * HID + k0);
        const int p  = k0 >> 5;
        const int kk = k0 & 31;
        const size_t dst = (size_t)p * 8192 + (size_t)SWZ(c, c * 32 + kk);
        const float xs[4] = {v.x, v.y, v.z, v.w};
        ushort hv[4], lv[4];
#pragma unroll
        for (int j = 0; j < 4; j++) {
            const ushort h = f2bf(xs[j]);
            hv[j] = h;
            lv[j] = f2bf(xs[j] - __uint_as_float(((unsigned)h) << 16));
        }
        *(ushort4*)(W1h + dst) = make_ushort4(hv[0], hv[1], hv[2], hv[3]);
        *(ushort4*)(W1l + dst) = make_ushort4(lv[0], lv[1], lv[2], lv[3]);
    } else {
        const int e  = blockIdx.x - 256;             // expert = B row, 0..63
        const int k0 = threadIdx.x * 4;              // 0..1020
        const float4 v = *(const float4*)(RW + (size_t)e * HID + k0);
        const float xs[4] = {v.x, v.y, v.z, v.w};
        ushort h[4], m[4], l[4];
#pragma unroll
        for (int j = 0; j < 4; j++) split3r(xs[j], h[j], m[j], l[j]);
        const int p  = k0 >> 5;
        const int kk = k0 & 31;
        const size_t dst = (size_t)p * 2048 + (size_t)SWZ(e, e * 32 + kk);
        *(ushort4*)(RWh + dst) = make_ushort4(h[0], h[1], h[2], h[3]);
        *(ushort4*)(RWm + dst) = make_ushort4(m[0], m[1], m[2], m[3]);
        *(ushort4*)(RWl + dst) = make_ushort4(l[0], l[1], l[2], l[3]);
    }
}

// ---------------------------------------------------------------------------
// Kernel 1 (v8, FUSED): router-logits (6-product exact split) + complexity
// predictor (3-product, bit-exact vs previous pred) in ONE X pass.
// Round-2 post-mortem: logits_mfma + pred_mfma together paid ~2.5 X passes
// (pred read X twice) and two pipeline fills; both sub-77µs so invisible in
// top-5 but ~100-140µs combined by arithmetic. Fusion: 64-tok blocks, 8
// waves. Wave w: row-pair rp=w>>2, col-group cg=w&3. Per k-panel: stage X
// (split3r, swizzled), global_load_lds W1/RW pre-swizzled panels; 12 logits
// MFMA + 24 pred MFMA per wave. s2 reduced in-LDS, stored (no atomics).
// (Round-3 resubmission: container failed twice = infra flake; source
// re-audited — gload_lds dest linear per wave, SWZ both-sides, bounds OK.)
// ---------------------------------------------------------------------------
__global__ __launch_bounds__(512, 4) void fused_mfma(
    const float* __restrict__ X,
    const ushort* __restrict__ RWh, const ushort* __restrict__ RWm,
    const ushort* __restrict__ RWl,
    const ushort* __restrict__ W1h, const ushort* __restrict__ W1l,
    const float* __restrict__ B1, const float* __restrict__ W2,
    float* __restrict__ logits, float* __restrict__ s2ws)
{
    __shared__ __align__(16) ushort Xh[2048], Xm[2048], Xl[2048];   // [64 tok][32 k]
    __shared__ __align__(16) ushort RBh[2048], RBm[2048], RBl[2048];// [64 exp][32 k]
    __shared__ __align__(16) ushort Wh[8192], Wl[8192];             // [256 col][32 k]
    __shared__ float red[4][64];

    const int tid  = threadIdx.x;
    const int lane = tid & 63;
    const int w    = tid >> 6;           // 0..7
    const int quad = lane >> 4, l15 = lane & 15;
    const int tok0 = blockIdx.x * 64;
    const int rp   = w >> 2;             // token row-pair (32 tok)
    const int cg   = w & 3;              // logits col-tile / pred col-group

    const int xrow = tid >> 3;           // 0..63
    const int xoff = (tid & 7) * 4;      // 0..28

    f32x4 accL[2];
    f32x4 accP[2][4];
#pragma unroll
    for (int f = 0; f < 2; f++) {
        accL[f] = (f32x4){0.f, 0.f, 0.f, 0.f};
#pragma unroll
        for (int j = 0; j < 4; j++) accP[f][j] = (f32x4){0.f, 0.f, 0.f, 0.f};
    }

    float w2r[4], b1r[4];
#pragma unroll
    for (int j = 0; j < 4; j++) {
        const int col = (cg * 4 + j) * 16 + l15;
        w2r[j] = W2[col];
        b1r[j] = B1[col];
    }

    const float* __restrict__ xsrc = X + (size_t)(tok0 + xrow) * HID + xoff;
    float4 xv = *(const float4*)(xsrc);              // p = 0 prefetch

    for (int p = 0; p < 32; ++p) {
        // ---- stage X (convert + swizzled LDS write) ----
        {
            const float xs[4] = {xv.x, xv.y, xv.z, xv.w};
            ushort hv[4], mv[4], lv[4];
#pragma unroll
            for (int j = 0; j < 4; j++) split3r(xs[j], hv[j], mv[j], lv[j]);
            const int us = SWZ(xrow, xrow * 32 + xoff);
            *(ushort4*)&Xh[us] = make_ushort4(hv[0], hv[1], hv[2], hv[3]);
            *(ushort4*)&Xm[us] = make_ushort4(mv[0], mv[1], mv[2], mv[3]);
            *(ushort4*)&Xl[us] = make_ushort4(lv[0], lv[1], lv[2], lv[3]);
        }
        // ---- stage W1 panels (2 x 16 KB) via global_load_lds ----
        {
            const size_t pb = (size_t)p * 8192;
            __builtin_amdgcn_global_load_lds(
                (const __attribute__((address_space(1))) void*)(W1h + pb + (size_t)tid * 8),
                (__attribute__((address_space(3))) void*)((char*)Wh + (size_t)tid * 16), 16, 0, 0);
            __builtin_amdgcn_global_load_lds(
                (const __attribute__((address_space(1))) void*)(W1h + pb + (size_t)(tid + 512) * 8),
                (__attribute__((address_space(3))) void*)((char*)Wh + (size_t)(tid + 512) * 16), 16, 0, 0);
            __builtin_amdgcn_global_load_lds(
                (const __attribute__((address_space(1))) void*)(W1l + pb + (size_t)tid * 8),
                (__attribute__((address_space(3))) void*)((char*)Wl + (size_t)tid * 16), 16, 0, 0);
            __builtin_amdgcn_global_load_lds(
                (const __attribute__((address_space(1))) void*)(W1l + pb + (size_t)(tid + 512) * 8),
                (__attribute__((address_space(3))) void*)((char*)Wl + (size_t)(tid + 512) * 16), 16, 0, 0);
        }
        // ---- stage RW panels (3 x 4 KB) ----
        {
            const size_t pb = (size_t)p * 2048;
            if (tid < 256) {
                __builtin_amdgcn_global_load_lds(
                    (const __attribute__((address_space(1))) void*)(RWh + pb + (size_t)tid * 8),
                    (__attribute__((address_space(3))) void*)((char*)RBh + (size_t)tid * 16), 16, 0, 0);
                __builtin_amdgcn_global_load_lds(
                    (const __attribute__((address_space(1))) void*)(RWl + pb + (size_t)tid * 8),
                    (__attribute__((address_space(3))) void*)((char*)RBl + (size_t)tid * 16), 16, 0, 0);
            } else {
                const int i2 = tid - 256;
                __builtin_amdgcn_global_load_lds(
                    (const __attribute__((address_space(1))) void*)(RWm + pb + (size_t)i2 * 8),
                    (__attribute__((address_space(3))) void*)((char*)RBm + (size_t)i2 * 16), 16, 0, 0);
            }
        }
        __syncthreads();

        // ---- prefetch next X tile to regs (hides under MFMA phase) ----
        xv = *(const float4*)(xsrc + ((p + 1) & 31) * 32);

        // ---- A fragments (shared by logits & pred) ----
        bf16x8 axh[2], axm[2], axl[2];
#pragma unroll
        for (int f = 0; f < 2; ++f) {
            const int ra = rp * 32 + f * 16 + l15;
            const int ua = SWZ(ra, ra * 32 + quad * 8);
            axh[f] = *(const bf16x8*)&Xh[ua];
            axm[f] = *(const bf16x8*)&Xm[ua];
            axl[f] = *(const bf16x8*)&Xl[ua];
        }

        // ---- logits: col-tile cg, 6-product exact split ----
        {
            const int rb = cg * 16 + l15;
            const int ub = SWZ(rb, rb * 32 + quad * 8);
            const bf16x8 rbh = *(const bf16x8*)&RBh[ub];
            const bf16x8 rbm = *(const bf16x8*)&RBm[ub];
            const bf16x8 rbl = *(const bf16x8*)&RBl[ub];
#pragma unroll
            for (int f = 0; f < 2; ++f) {
                accL[f] = __builtin_amdgcn_mfma_f32_16x16x32_bf16(axh[f], rbh, accL[f], 0, 0, 0);
                accL[f] = __builtin_amdgcn_mfma_f32_16x16x32_bf16(axm[f], rbh, accL[f], 0, 0, 0);
                accL[f] = __builtin_amdgcn_mfma_f32_16x16x32_bf16(axh[f], rbm, accL[f], 0, 0, 0);
                accL[f] = __builtin_amdgcn_mfma_f32_16x16x32_bf16(axl[f], rbh, accL[f], 0, 0, 0);
                accL[f] = __builtin_amdgcn_mfma_f32_16x16x32_bf16(axh[f], rbl, accL[f], 0, 0, 0);
                accL[f] = __builtin_amdgcn_mfma_f32_16x16x32_bf16(axm[f], rbm, accL[f], 0, 0, 0);
            }
        }

        // ---- pred: col-tiles cg*4..cg*4+3, 3 products (bit-exact order) ----
#pragma unroll
        for (int j = 0; j < 4; ++j) {
            const int rw = (cg * 4 + j) * 16 + l15;
            const int uw = SWZ(rw, rw * 32 + quad * 8);
            const bf16x8 bwh = *(const bf16x8*)&Wh[uw];
            const bf16x8 bwl = *(const bf16x8*)&Wl[uw];
#pragma unroll
            for (int f = 0; f < 2; ++f) {
                accP[f][j] = __builtin_amdgcn_mfma_f32_16x16x32_bf16(axh[f], bwh, accP[f][j], 0, 0, 0);
                accP[f][j] = __builtin_amdgcn_mfma_f32_16x16x32_bf16(axm[f], bwh, accP[f][j], 0, 0, 0);
                accP[f][j] = __builtin_amdgcn_mfma_f32_16x16x32_bf16(axh[f], bwl, accP[f][j], 0, 0, 0);
            }
        }
        __syncthreads();
    }

    // ---- logits epilogue (C/D: row = quad*4 + r, col = l15) ----
#pragma unroll
    for (int f = 0; f < 2; ++f)
#pragma unroll
        for (int r = 0; r < 4; ++r)
            logits[(size_t)(tok0 + (rp * 2 + f) * 16 + quad * 4 + r) * NEXP
                   + cg * 16 + l15] = accL[f][r];

    // ---- pred epilogue: bias+ReLU+w2 dot, in-LDS cross-wave reduce ----
#pragma unroll
    for (int f = 0; f < 2; ++f) {
#pragma unroll
        for (int r = 0; r < 4; ++r) {
            float s = 0.f;
#pragma unroll
            for (int j = 0; j < 4; ++j) {
                const float hval = accP[f][j][r] + b1r[j];
                s = fmaf(w2r[j], fmaxf(hval, 0.f), s);
            }
            s += __shfl_xor(s, 1);
            s += __shfl_xor(s, 2);
            s += __shfl_xor(s, 4);
            s += __shfl_xor(s, 8);
            if (l15 == 0)
                red[cg][rp * 32 + f * 16 + quad * 4 + r] = s;
        }
    }
    __syncthreads();
    if (tid < 64)
        s2ws[tok0 + tid] = red[0][tid] + red[1][tid] + red[2][tid] + red[3][tid];
}

// ---------------------------------------------------------------------------
// Kernel 3: per-token routing (unchanged, proven fast)
// ---------------------------------------------------------------------------
__global__ __launch_bounds__(64) void route_kernel(
    const float* __restrict__ logits, const float* __restrict__ s2ws,
    const float* __restrict__ B2, float* __restrict__ sel,
    float* __restrict__ wts, float* __restrict__ load_sum,
    float* __restrict__ ent_sum)
{
    const int lane = threadIdx.x;
    const int tok  = blockIdx.x * 64 + lane;

    float r[64];
    const float* lr = logits + (size_t)tok * NEXP;
#pragma unroll
    for (int e4 = 0; e4 < 16; e4++) {
        float4 v = *(const float4*)(lr + e4 * 4);
        r[e4 * 4 + 0] = v.x; r[e4 * 4 + 1] = v.y;
        r[e4 * 4 + 2] = v.z; r[e4 * 4 + 3] = v.w;
    }

    float v0 = -1e30f, v1 = -1e30f, v2 = -1e30f, v3 = -1e30f;
    int   i0 = 0, i1 = 0, i2 = 0, i3 = 0;
#pragma unroll
    for (int e = 0; e < 64; e++) {
        const float v = r[e];
        if (v > v3) {
            if (v > v2) {
                if (v > v1) {
                    if (v > v0) { v3=v2;i3=i2; v2=v1;i2=i1; v1=v0;i1=i0; v0=v;i0=e; }
                    else        { v3=v2;i3=i2; v2=v1;i2=i1; v1=v;i1=e; }
                } else          { v3=v2;i3=i2; v2=v;i2=e; }
            } else              { v3=v;i3=e; }
        }
    }

    const float s2 = s2ws[tok] + B2[0];
    const bool k4 = (s2 > 0.f);

    float w0, w1v, w2v, w3v;
    int   s1i, s2i, s3i;
    if (k4) {
        const float e0 = expf(v0 - v0), e1 = expf(v1 - v0);
        const float e2 = expf(v2 - v0), e3 = expf(v3 - v0);
        const float inv4 = 1.f / (e0 + e1 + e2 + e3);
        w0 = e0 * inv4; w1v = e1 * inv4; w2v = e2 * inv4; w3v = e3 * inv4;
        s1i = i1; s2i = i2; s3i = i3;
    } else {
        w0 = 1.f; w1v = 0.f; w2v = 0.f; w3v = 0.f;
        s1i = 0; s2i = 0; s3i = 0;
    }
    {
        float4 sv = {(float)i0, (float)s1i, (float)s2i, (float)s3i};
        float4 wv = {w0, w1v, w2v, w3v};
        *(float4*)(sel + (size_t)tok * 4) = sv;
        *(float4*)(wts + (size_t)tok * 4) = wv;
    }

    const float mx = v0;
    float S = 0.f, pz = 0.f;
#pragma unroll
    for (int e = 0; e < 64; e++) {
        const float z = r[e] - mx;
        const float t = expf(z);
        S += t; pz = fmaf(t, z, pz);
        r[e] = t;
    }
    const float inv = 1.f / S;
    float ent = logf(S) - pz * inv;

    float myload = 0.f;
#pragma unroll
    for (int e = 0; e < 64; e++) {
        float s = r[e] * inv;
        s += __shfl_xor(s, 1);
        s += __shfl_xor(s, 2);
        s += __shfl_xor(s, 4);
        s += __shfl_xor(s, 8);
        s += __shfl_xor(s, 16);
        s += __shfl_xor(s, 32);
        if (lane == e) myload = s;
    }
    atomicAdd(&load_sum[lane], myload);

    ent += __shfl_xor(ent, 1);
    ent += __shfl_xor(ent, 2);
    ent += __shfl_xor(ent, 4);
    ent += __shfl_xor(ent, 8);
    ent += __shfl_xor(ent, 16);
    ent += __shfl_xor(ent, 32);
    if (lane == 0) atomicAdd(ent_sum, ent);
}

__global__ void finalize_kernel(const float* __restrict__ load_sum,
                                const float* __restrict__ ent_sum,
                                float* __restrict__ out_scal)
{
    const int lane = threadIdx.x;
    const float le = load_sum[lane] * (1.f / (float)NTOK);
    float s = le;
#pragma unroll
    for (int o = 32; o >= 1; o >>= 1) s += __shfl_xor(s, o);
    const float mean = s * (1.f / 64.f);
    const float d = le - mean;
    float v = d * d;
#pragma unroll
    for (int o = 32; o >= 1; o >>= 1) v += __shfl_xor(v, o);
    if (lane == 0) {
        out_scal[0] = v * (1.f / 63.f);
        out_scal[1] = ent_sum[0] * (1.f / (float)NTOK);
    }
}

extern "C" void kernel_launch(void* const* d_in, const int* in_sizes, int n_in,
                              void* d_out, int out_size, void* d_ws, size_t ws_size,
                              hipStream_t stream) {
    const float* X  = (const float*)d_in[0];
    const float* RW = (const float*)d_in[1];
    const float* W1 = (const float*)d_in[2];
    const float* B1 = (const float*)d_in[3];
    const float* W2 = (const float*)d_in[4];
    const float* B2 = (const float*)d_in[5];

    float* out    = (float*)d_out;
    float* logits = out;
    float* sel    = out + (size_t)NTOK * NEXP;
    float* wts    = sel + (size_t)NTOK * 4;
    float* scal   = wts + (size_t)NTOK * 4;

    float* s2ws     = (float*)d_ws;                       // [32768] (fully written)
    float* load_sum = s2ws + NTOK;                        // [64]
    float* ent_sum  = load_sum + 64;                      // [1]
    ushort* W1h = (ushort*)(s2ws + NTOK + 256);           // 512 KB, pre-swizzled [32p][f(256x32)]
    ushort* W1l = W1h + (size_t)H4 * HID;                 // 512 KB
    ushort* RWh = W1l + (size_t)H4 * HID;                 // 128 KB, pre-swizzled [32p][f(64x32)]
    ushort* RWm = RWh + (size_t)NEXP * HID;               // 128 KB
    ushort* RWl = RWm + (size_t)NEXP * HID;               // 128 KB

    hipMemsetAsync(load_sum, 0, 65 * sizeof(float), stream);

    prep_kernel<<<320, 256, 0, stream>>>(W1, RW, W1h, W1l, RWh, RWm, RWl);
    fused_mfma<<<NTOK / 64, 512, 0, stream>>>(X, RWh, RWm, RWl, W1h, W1l, B1, W2, logits, s2ws);
    route_kernel<<<NTOK / 64, 64, 0, stream>>>(logits, s2ws, B2, sel, wts, load_sum, ent_sum);
    finalize_kernel<<<1, 64, 0, stream>>>(load_sum, ent_sum, scal);
}